// Round 3
// baseline (163.370 us; speedup 1.0000x reference)
//
#include <hip/hip_runtime.h>

// PillarVFE fused: BN-stats via feature moments (k1,k2), then k3 does
// x = a*(W'.xyzw + d_v) + b entirely inside one MFMA pair per voxel:
//   B columns pre-scaled by a (bf16), C initialized to (row<cnt ? a*d+b : b) in fp32,
//   epilogue = max over 32 rows + relu. K=4 real (10-feature algebra folded).

typedef __attribute__((ext_vector_type(8))) short short8;     // 8 bf16
typedef __attribute__((ext_vector_type(16))) float floatx16;  // 32x32 MFMA C/D

namespace {
constexpr int V_    = 100000;
constexpr int P_    = 32;
constexpr int COUT  = 64;
constexpr int NF    = 10;
constexpr int NMOM  = 65;
constexpr int PSTRIDE = 72;
constexpr int K1_BLOCKS = 512;
constexpr int K3_BLOCKS = 1536;   // 6144 waves

constexpr float VX_ = 0.16f, VY_ = 0.16f, VZ_ = 4.0f;
constexpr float XOFF_ = 0.08f, YOFF_ = -39.60f, ZOFF_ = -1.0f;
constexpr float EPS_ = 0.001f;
}

__device__ __forceinline__ short f2bf(float x) {  // RNE
  unsigned u = __builtin_bit_cast(unsigned, x);
  u += 0x7fffu + ((u >> 16) & 1u);
  return (short)(u >> 16);
}

// Pass 1: 65 feature moments (wave acc -> block reduce -> 512 rows) + per-voxel raw xyz sums.
__global__ __launch_bounds__(256) void k1_stats(
    const float* __restrict__ vf, const int* __restrict__ npts,
    const int* __restrict__ coords, float* __restrict__ partials,
    float* __restrict__ meanws)
{
  float acc[NMOM];
  #pragma unroll
  for (int i = 0; i < NMOM; ++i) acc[i] = 0.f;

  const int tid = threadIdx.x;
  const int sub = tid >> 5;
  const int p   = tid & 31;

  for (int base = blockIdx.x * 8; base < V_; base += K1_BLOCKS * 8) {
    int v = base + sub;
    bool vvalid = (v < V_);
    float4 pt = make_float4(0.f, 0.f, 0.f, 0.f);
    int cnt = 0;
    int4 cd = make_int4(0, 0, 0, 0);
    if (vvalid) {
      pt  = ((const float4*)vf)[v * P_ + p];
      cnt = npts[v];
      cd  = ((const int4*)coords)[v];
    }
    // raw point sums (reference sums ALL 32 rows, divides by cnt)
    float sx = pt.x, sy = pt.y, sz = pt.z;
    #pragma unroll
    for (int m = 16; m >= 1; m >>= 1) {
      sx += __shfl_xor(sx, m, 32);
      sy += __shfl_xor(sy, m, 32);
      sz += __shfl_xor(sz, m, 32);
    }
    if (vvalid && p == 0)
      ((float4*)meanws)[v] = make_float4(sx, sy, sz, 0.f);

    float cf = (cnt > 0) ? (float)cnt : 1.f;
    float mx = sx / cf, my = sy / cf, mz = sz / cf;
    float cx = (float)cd.w * VX_ + XOFF_;
    float cy = (float)cd.z * VY_ + YOFF_;
    float cz = (float)cd.y * VZ_ + ZOFF_;
    float msk = (vvalid && p < cnt) ? 1.0f : 0.0f;
    float f[NF];
    f[0] = pt.x * msk; f[1] = pt.y * msk; f[2] = pt.z * msk; f[3] = pt.w * msk;
    f[4] = (pt.x - mx) * msk; f[5] = (pt.y - my) * msk; f[6] = (pt.z - mz) * msk;
    f[7] = (pt.x - cx) * msk; f[8] = (pt.y - cy) * msk; f[9] = (pt.z - cz) * msk;

    #pragma unroll
    for (int c = 0; c < NF; ++c) acc[c] += f[c];
    int idx = NF;
    #pragma unroll
    for (int c = 0; c < NF; ++c)
      #pragma unroll
      for (int c2 = c; c2 < NF; ++c2)
        acc[idx++] += f[c] * f[c2];
  }

  #pragma unroll
  for (int i = 0; i < NMOM; ++i) {
    float a = acc[i];
    #pragma unroll
    for (int m = 32; m >= 1; m >>= 1) a += __shfl_xor(a, m, 64);
    acc[i] = a;
  }

  __shared__ float red[4][NMOM];
  if ((tid & 63) == 0) {
    int w = tid >> 6;
    #pragma unroll
    for (int i = 0; i < NMOM; ++i) red[w][i] = acc[i];
  }
  __syncthreads();
  if (tid < NMOM) {
    partials[blockIdx.x * PSTRIDE + tid] =
        (red[0][tid] + red[1][tid]) + (red[2][tid] + red[3][tid]);
  }
}

// Pass 2: reduce 512 rows -> a,b per channel.
__global__ __launch_bounds__(576) void k2_finalize(
    const float* __restrict__ partials, const float* __restrict__ Wm,
    const float* __restrict__ gamma, const float* __restrict__ beta,
    float* __restrict__ ab)
{
  __shared__ float s1[8 * NMOM];
  __shared__ double S[NMOM];
  const int t = threadIdx.x;

  if (t < 8 * NMOM) {
    int col = t % NMOM, chunk = t / NMOM;
    float acc = 0.f;
    int base = chunk * 64;
    #pragma unroll 8
    for (int i = 0; i < 64; ++i) acc += partials[(base + i) * PSTRIDE + col];
    s1[chunk * NMOM + col] = acc;
  }
  __syncthreads();
  if (t < NMOM) {
    double d = 0.0;
    #pragma unroll
    for (int c = 0; c < 8; ++c) d += (double)s1[c * NMOM + t];
    S[t] = d;
  }
  __syncthreads();
  if (t < COUT) {
    const double N = (double)V_ * (double)P_;
    double w[NF];
    #pragma unroll
    for (int c = 0; c < NF; ++c) w[c] = (double)Wm[t * NF + c];
    double mean = 0.0;
    #pragma unroll
    for (int c = 0; c < NF; ++c) mean += w[c] * S[c];
    mean /= N;
    double ex2 = 0.0;
    int idx = NF;
    #pragma unroll
    for (int c = 0; c < NF; ++c)
      #pragma unroll
      for (int c2 = c; c2 < NF; ++c2) {
        double coef = (c == c2) ? 1.0 : 2.0;
        ex2 += coef * w[c] * w[c2] * S[idx++];
      }
    ex2 /= N;
    double var = ex2 - mean * mean;
    double rs = 1.0 / sqrt(var + (double)EPS_);
    double a = (double)gamma[t] * rs;
    double b = (double)beta[t] - mean * a;
    ab[t] = (float)a;
    ab[COUT + t] = (float)b;
  }
}

// Pass 3: one wave = one voxel/iter. A = masked raw xyzw (K=4), B = a*W' (bf16),
// C init = (row<cnt ? a*d+b : b) fp32, epilogue = max + relu.
__global__ __launch_bounds__(256) void k3_mfma(
    const float* __restrict__ vf, const int* __restrict__ npts,
    const int* __restrict__ coords, const float* __restrict__ Wm,
    const float* __restrict__ ab, const float* __restrict__ meanws,
    float* __restrict__ out)
{
  const int tid  = threadIdx.x;
  const int lane = tid & 63;
  const int p    = lane & 31;   // A row (point) / C column (channel in group)
  const int half = lane >> 5;
  const int waveG = blockIdx.x * 4 + (tid >> 6);
  const int nW = K3_BLOCKS * 4;

  const int n0 = p, n1 = 32 + p;
  // W rows 4..9 for the d computation (both channel groups)
  const float w40 = Wm[n0*NF+4], w50 = Wm[n0*NF+5], w60 = Wm[n0*NF+6];
  const float w70 = Wm[n0*NF+7], w80 = Wm[n0*NF+8], w90 = Wm[n0*NF+9];
  const float w41 = Wm[n1*NF+4], w51 = Wm[n1*NF+5], w61 = Wm[n1*NF+6];
  const float w71 = Wm[n1*NF+7], w81 = Wm[n1*NF+8], w91 = Wm[n1*NF+9];
  const float a0 = ab[n0], b0 = ab[COUT + n0];
  const float a1 = ab[n1], b1 = ab[COUT + n1];

  // B fragments: column n = lane&31, k = half*8+j; only k<4 nonzero (W' scaled by a)
  short8 bf0, bf1;
  #pragma unroll
  for (int j = 0; j < 8; ++j) { bf0[j] = 0; bf1[j] = 0; }
  if (half == 0) {
    bf0[0] = f2bf(a0 * (Wm[n0*NF+0] + w40 + w70));
    bf0[1] = f2bf(a0 * (Wm[n0*NF+1] + w50 + w80));
    bf0[2] = f2bf(a0 * (Wm[n0*NF+2] + w60 + w90));
    bf0[3] = f2bf(a0 * Wm[n0*NF+3]);
    bf1[0] = f2bf(a1 * (Wm[n1*NF+0] + w41 + w71));
    bf1[1] = f2bf(a1 * (Wm[n1*NF+1] + w51 + w81));
    bf1[2] = f2bf(a1 * (Wm[n1*NF+2] + w61 + w91));
    bf1[3] = f2bf(a1 * Wm[n1*NF+3]);
  }

  for (int v = waveG; v < V_; v += nW) {
    const int vu = __builtin_amdgcn_readfirstlane(v);
    float4 pt = ((const float4*)vf)[vu * P_ + p];
    int  cnt = npts[vu];
    int4 cd  = ((const int4*)coords)[vu];
    float4 sm = ((const float4*)meanws)[vu];

    float cf = (float)cnt;
    float mx = sm.x / cf, my = sm.y / cf, mz = sm.z / cf;
    float cx = (float)cd.w * VX_ + XOFF_;
    float cy = (float)cd.z * VY_ + YOFF_;
    float cz = (float)cd.y * VZ_ + ZOFF_;
    float d0 = -(mx*w40 + my*w50 + mz*w60 + cx*w70 + cy*w80 + cz*w90);
    float d1 = -(mx*w41 + my*w51 + mz*w61 + cx*w71 + cy*w81 + cz*w91);
    float q0 = fmaf(a0, d0, b0);
    float q1 = fmaf(a1, d1, b1);

    // A fragment: row = p, k = half*8+j; only half0 k=0..3 real, masked by p<cnt
    bool am = (half == 0) && (p < cnt);
    short8 af;
    af[0] = f2bf(am ? pt.x : 0.f);
    af[1] = f2bf(am ? pt.y : 0.f);
    af[2] = f2bf(am ? pt.z : 0.f);
    af[3] = f2bf(am ? pt.w : 0.f);
    #pragma unroll
    for (int j = 4; j < 8; ++j) af[j] = 0;

    floatx16 c0, c1;
    #pragma unroll
    for (int i = 0; i < 16; ++i) {
      int row = (i & 3) + 8 * (i >> 2) + 4 * half;
      bool vld = row < cnt;
      c0[i] = vld ? q0 : b0;   // invalid point: x=0 -> a*0+b = b
      c1[i] = vld ? q1 : b1;
    }
    c0 = __builtin_amdgcn_mfma_f32_32x32x16_bf16(af, bf0, c0, 0, 0, 0);
    c1 = __builtin_amdgcn_mfma_f32_32x32x16_bf16(af, bf1, c1, 0, 0, 0);

    float m0 = c0[0], m1 = c1[0];
    #pragma unroll
    for (int i = 1; i < 16; ++i) {
      m0 = fmaxf(m0, c0[i]);
      m1 = fmaxf(m1, c1[i]);
    }
    m0 = fmaxf(m0, __shfl_xor(m0, 32, 64));
    m1 = fmaxf(m1, __shfl_xor(m1, 32, 64));
    float y = half ? m1 : m0;
    out[vu * COUT + lane] = fmaxf(y, 0.f);
  }
}

extern "C" void kernel_launch(void* const* d_in, const int* in_sizes, int n_in,
                              void* d_out, int out_size, void* d_ws, size_t ws_size,
                              hipStream_t stream)
{
  const float* vf     = (const float*)d_in[0];
  const int*   npts   = (const int*)d_in[1];
  const int*   coords = (const int*)d_in[2];
  const float* Wm     = (const float*)d_in[3];
  const float* gamma  = (const float*)d_in[4];
  const float* beta   = (const float*)d_in[5];
  float* out = (float*)d_out;

  float* ws = (float*)d_ws;
  float* partials = ws;                              // 512*72 floats
  float* ab       = ws + K1_BLOCKS * PSTRIDE;        // 128 floats
  float* meanws   = ws + K1_BLOCKS * PSTRIDE + 128;  // V_*4 floats (all written by k1)

  k1_stats<<<K1_BLOCKS, 256, 0, stream>>>(vf, npts, coords, partials, meanws);
  k2_finalize<<<1, 576, 0, stream>>>(partials, Wm, gamma, beta, ab);
  k3_mfma<<<K3_BLOCKS, 256, 0, stream>>>(vf, npts, coords, Wm, ab, meanws, out);
}

// Round 4
// 156.787 us; speedup vs baseline: 1.0420x; 1.0420x over previous
//
#include <hip/hip_runtime.h>

// PillarVFE fused. k1: feature moments (65) + per-voxel packed record
// (-mx,-my,-mz,-cx,-cy,-cz bf16, cnt). k2: reduce -> per-channel a,b.
// k3: A = [xyzw, -mean, -center]*mask in K-slots, B = a*W'' (bf16),
// C = 0 -> D = a*x exactly (invalid rows 0); out = relu(b + max_rows D).

typedef __attribute__((ext_vector_type(8))) short short8;     // 8 bf16
typedef __attribute__((ext_vector_type(16))) float floatx16;  // 32x32 MFMA C/D

namespace {
constexpr int V_    = 100000;
constexpr int P_    = 32;
constexpr int COUT  = 64;
constexpr int NF    = 10;
constexpr int NMOM  = 65;
constexpr int PSTRIDE = 72;
constexpr int K1_BLOCKS = 1024;
constexpr int K3_BLOCKS = 2048;   // 8192 waves, ~12 voxels/wave

constexpr float VX_ = 0.16f, VY_ = 0.16f, VZ_ = 4.0f;
constexpr float XOFF_ = 0.08f, YOFF_ = -39.60f, ZOFF_ = -1.0f;
constexpr float EPS_ = 0.001f;
}

__device__ __forceinline__ unsigned f2bfu(float x) {  // RNE -> 16-bit value
  unsigned u = __builtin_bit_cast(unsigned, x);
  u += 0x7fffu + ((u >> 16) & 1u);
  return u >> 16;
}

// Pass 1: 65 feature moments (wave acc -> block reduce -> 1024 rows)
// + per-voxel record {pack(-mx,-my), pack(-mz,-cx), pack(-cy,-cz), cnt}.
__global__ __launch_bounds__(256) void k1_stats(
    const float* __restrict__ vf, const int* __restrict__ npts,
    const int* __restrict__ coords, float* __restrict__ partials,
    int4* __restrict__ meanws)
{
  float acc[NMOM];
  #pragma unroll
  for (int i = 0; i < NMOM; ++i) acc[i] = 0.f;

  const int tid = threadIdx.x;
  const int sub = tid >> 5;
  const int p   = tid & 31;

  for (int base = blockIdx.x * 8; base < V_; base += K1_BLOCKS * 8) {
    int v = base + sub;
    bool vvalid = (v < V_);
    float4 pt = make_float4(0.f, 0.f, 0.f, 0.f);
    int cnt = 0;
    int4 cd = make_int4(0, 0, 0, 0);
    if (vvalid) {
      pt  = ((const float4*)vf)[v * P_ + p];
      cnt = npts[v];
      cd  = ((const int4*)coords)[v];
    }
    float sx = pt.x, sy = pt.y, sz = pt.z;
    #pragma unroll
    for (int m = 16; m >= 1; m >>= 1) {
      sx += __shfl_xor(sx, m, 32);
      sy += __shfl_xor(sy, m, 32);
      sz += __shfl_xor(sz, m, 32);
    }
    float cf = (cnt > 0) ? (float)cnt : 1.f;
    float mx = sx / cf, my = sy / cf, mz = sz / cf;
    float cx = (float)cd.w * VX_ + XOFF_;
    float cy = (float)cd.z * VY_ + YOFF_;
    float cz = (float)cd.y * VZ_ + ZOFF_;

    if (vvalid && p == 0) {
      unsigned nm01 = f2bfu(-mx) | (f2bfu(-my) << 16);
      unsigned nm23 = f2bfu(-mz) | (f2bfu(-cx) << 16);
      unsigned nm45 = f2bfu(-cy) | (f2bfu(-cz) << 16);
      meanws[v] = make_int4((int)nm01, (int)nm23, (int)nm45, cnt);
    }

    float msk = (vvalid && p < cnt) ? 1.0f : 0.0f;
    float f[NF];
    f[0] = pt.x * msk; f[1] = pt.y * msk; f[2] = pt.z * msk; f[3] = pt.w * msk;
    f[4] = (pt.x - mx) * msk; f[5] = (pt.y - my) * msk; f[6] = (pt.z - mz) * msk;
    f[7] = (pt.x - cx) * msk; f[8] = (pt.y - cy) * msk; f[9] = (pt.z - cz) * msk;

    #pragma unroll
    for (int c = 0; c < NF; ++c) acc[c] += f[c];
    int idx = NF;
    #pragma unroll
    for (int c = 0; c < NF; ++c)
      #pragma unroll
      for (int c2 = c; c2 < NF; ++c2)
        acc[idx++] += f[c] * f[c2];
  }

  #pragma unroll
  for (int i = 0; i < NMOM; ++i) {
    float a = acc[i];
    #pragma unroll
    for (int m = 32; m >= 1; m >>= 1) a += __shfl_xor(a, m, 64);
    acc[i] = a;
  }

  __shared__ float red[4][NMOM];
  if ((tid & 63) == 0) {
    int w = tid >> 6;
    #pragma unroll
    for (int i = 0; i < NMOM; ++i) red[w][i] = acc[i];
  }
  __syncthreads();
  if (tid < NMOM) {
    partials[blockIdx.x * PSTRIDE + tid] =
        (red[0][tid] + red[1][tid]) + (red[2][tid] + red[3][tid]);
  }
}

// Pass 2: reduce 1024 rows -> a,b per channel.
__global__ __launch_bounds__(576) void k2_finalize(
    const float* __restrict__ partials, const float* __restrict__ Wm,
    const float* __restrict__ gamma, const float* __restrict__ beta,
    float* __restrict__ ab)
{
  __shared__ float s1[8 * NMOM];
  __shared__ double S[NMOM];
  const int t = threadIdx.x;

  if (t < 8 * NMOM) {
    int col = t % NMOM, chunk = t / NMOM;   // 8 chunks x 128 rows
    float acc = 0.f;
    int base = chunk * 128;
    #pragma unroll 8
    for (int i = 0; i < 128; ++i) acc += partials[(base + i) * PSTRIDE + col];
    s1[chunk * NMOM + col] = acc;
  }
  __syncthreads();
  if (t < NMOM) {
    double d = 0.0;
    #pragma unroll
    for (int c = 0; c < 8; ++c) d += (double)s1[c * NMOM + t];
    S[t] = d;
  }
  __syncthreads();
  if (t < COUT) {
    const double N = (double)V_ * (double)P_;
    double w[NF];
    #pragma unroll
    for (int c = 0; c < NF; ++c) w[c] = (double)Wm[t * NF + c];
    double mean = 0.0;
    #pragma unroll
    for (int c = 0; c < NF; ++c) mean += w[c] * S[c];
    mean /= N;
    double ex2 = 0.0;
    int idx = NF;
    #pragma unroll
    for (int c = 0; c < NF; ++c)
      #pragma unroll
      for (int c2 = c; c2 < NF; ++c2) {
        double coef = (c == c2) ? 1.0 : 2.0;
        ex2 += coef * w[c] * w[c2] * S[idx++];
      }
    ex2 /= N;
    double var = ex2 - mean * mean;
    double rs = 1.0 / sqrt(var + (double)EPS_);
    double a = (double)gamma[t] * rs;
    double b = (double)beta[t] - mean * a;
    ab[t] = (float)a;
    ab[COUT + t] = (float)b;
  }
}

// Pass 3: one wave = one voxel/iter. A K-slots = [xyzw, -m, -ctr]*mask, C=0,
// D = a*x exactly; out = relu(b + max over 32 rows).
__global__ __launch_bounds__(256) void k3_mfma(
    const float* __restrict__ vf, const float* __restrict__ Wm,
    const float* __restrict__ ab, const int4* __restrict__ meanws,
    float* __restrict__ out)
{
  const int tid  = threadIdx.x;
  const int lane = tid & 63;
  const int p    = lane & 31;   // A row (point) / C column (channel in group)
  const int half = lane >> 5;
  const int waveG = blockIdx.x * 4 + (tid >> 6);
  const int nW = K3_BLOCKS * 4;

  // B fragments: B[k][n], n = lane&31, k = half*8+j.
  // k0..3: a*(W0+W4+W7, W1+W5+W8, W2+W6+W9, W3); k4..9: a*(W4..W9).
  const float a0 = ab[p],      b0 = ab[COUT + p];
  const float a1 = ab[32 + p], b1 = ab[COUT + 32 + p];
  short8 bf0, bf1;
  {
    const float* w0 = &Wm[p * NF];
    const float* w1 = &Wm[(32 + p) * NF];
    float t0[NF], t1[NF];
    t0[0] = a0 * (w0[0] + w0[4] + w0[7]);
    t0[1] = a0 * (w0[1] + w0[5] + w0[8]);
    t0[2] = a0 * (w0[2] + w0[6] + w0[9]);
    t0[3] = a0 * w0[3];
    t1[0] = a1 * (w1[0] + w1[4] + w1[7]);
    t1[1] = a1 * (w1[1] + w1[5] + w1[8]);
    t1[2] = a1 * (w1[2] + w1[6] + w1[9]);
    t1[3] = a1 * w1[3];
    #pragma unroll
    for (int k = 4; k < NF; ++k) { t0[k] = a0 * w0[k]; t1[k] = a1 * w1[k]; }

    uint4 bd0, bd1;
    unsigned p001 = f2bfu(t0[0]) | (f2bfu(t0[1]) << 16);
    unsigned p023 = f2bfu(t0[2]) | (f2bfu(t0[3]) << 16);
    unsigned p045 = f2bfu(t0[4]) | (f2bfu(t0[5]) << 16);
    unsigned p067 = f2bfu(t0[6]) | (f2bfu(t0[7]) << 16);
    unsigned p089 = f2bfu(t0[8]) | (f2bfu(t0[9]) << 16);
    unsigned p101 = f2bfu(t1[0]) | (f2bfu(t1[1]) << 16);
    unsigned p123 = f2bfu(t1[2]) | (f2bfu(t1[3]) << 16);
    unsigned p145 = f2bfu(t1[4]) | (f2bfu(t1[5]) << 16);
    unsigned p167 = f2bfu(t1[6]) | (f2bfu(t1[7]) << 16);
    unsigned p189 = f2bfu(t1[8]) | (f2bfu(t1[9]) << 16);
    bd0.x = half ? p089 : p001;  bd0.y = half ? 0u : p023;
    bd0.z = half ? 0u : p045;    bd0.w = half ? 0u : p067;
    bd1.x = half ? p189 : p101;  bd1.y = half ? 0u : p123;
    bd1.z = half ? 0u : p145;    bd1.w = half ? 0u : p167;
    bf0 = __builtin_bit_cast(short8, bd0);
    bf1 = __builtin_bit_cast(short8, bd1);
  }

  for (int v = waveG; v < V_; v += nW) {
    const int vu = __builtin_amdgcn_readfirstlane(v);
    const int4 rec = meanws[vu];                       // scalar 16B load
    const float4 pt = ((const float4*)vf)[vu * P_ + p];
    const int cnt = rec.w;
    const bool pm = p < cnt;

    unsigned dx = f2bfu(pm ? pt.x : 0.f) | (f2bfu(pm ? pt.y : 0.f) << 16);
    unsigned dy = f2bfu(pm ? pt.z : 0.f) | (f2bfu(pm ? pt.w : 0.f) << 16);
    unsigned m01 = pm ? (unsigned)rec.x : 0u;
    unsigned m23 = pm ? (unsigned)rec.y : 0u;
    unsigned m45 = pm ? (unsigned)rec.z : 0u;
    uint4 adw;
    adw.x = half ? m45 : dx;
    adw.y = half ? 0u  : dy;
    adw.z = half ? 0u  : m01;
    adw.w = half ? 0u  : m23;
    short8 af = __builtin_bit_cast(short8, adw);

    floatx16 c0 = {}, c1 = {};
    c0 = __builtin_amdgcn_mfma_f32_32x32x16_bf16(af, bf0, c0, 0, 0, 0);
    c1 = __builtin_amdgcn_mfma_f32_32x32x16_bf16(af, bf1, c1, 0, 0, 0);

    float m0 = c0[0], m1 = c1[0];
    #pragma unroll
    for (int i = 1; i < 16; ++i) {
      m0 = fmaxf(m0, c0[i]);
      m1 = fmaxf(m1, c1[i]);
    }
    m0 = fmaxf(m0, __shfl_xor(m0, 32, 64));
    m1 = fmaxf(m1, __shfl_xor(m1, 32, 64));
    float y = half ? fmaxf(b1 + m1, 0.f) : fmaxf(b0 + m0, 0.f);
    out[vu * COUT + lane] = y;
  }
}

extern "C" void kernel_launch(void* const* d_in, const int* in_sizes, int n_in,
                              void* d_out, int out_size, void* d_ws, size_t ws_size,
                              hipStream_t stream)
{
  const float* vf     = (const float*)d_in[0];
  const int*   npts   = (const int*)d_in[1];
  const int*   coords = (const int*)d_in[2];
  const float* Wm     = (const float*)d_in[3];
  const float* gamma  = (const float*)d_in[4];
  const float* beta   = (const float*)d_in[5];
  float* out = (float*)d_out;

  float* ws = (float*)d_ws;
  float* partials = ws;                               // 1024*72 floats
  float* ab       = ws + K1_BLOCKS * PSTRIDE;         // 128 floats
  int4*  meanws   = (int4*)(ws + K1_BLOCKS * PSTRIDE + 128);  // V_ int4

  k1_stats<<<K1_BLOCKS, 256, 0, stream>>>(vf, npts, coords, partials, meanws);
  k2_finalize<<<1, 576, 0, stream>>>(partials, Wm, gamma, beta, ab);
  k3_mfma<<<K3_BLOCKS, 256, 0, stream>>>(vf, Wm, ab, meanws, out);
}